// Round 1
// baseline (693.245 us; speedup 1.0000x reference)
//
#include <hip/hip_runtime.h>
#include <math.h>

// Problem constants (fixed by the reference)
#define BB  4096
#define LL  168
#define AA  128
#define FNN 32

// One block per batch sample. 256 threads = 4 waves.
// Lane ln owns f = {2*ln, 2*ln+1}; wave w owns n = [8w, 8w+8).
// cv tile = 2x8 fp32 registers per thread.
__global__ __launch_bounds__(256, 4)
void tpa_fused(const float* __restrict__ query,
               const float* __restrict__ attn_states,
               const float* __restrict__ W_q,
               const float* __restrict__ conv_k,
               const float* __restrict__ conv_b,
               const float* __restrict__ W_out,
               const float* __restrict__ b_out,
               float* __restrict__ out_attns,   // (B, A)
               float* __restrict__ out_states)  // (B, L-1, A)
{
    const int b    = blockIdx.x;
    const int t    = threadIdx.x;
    const int lane = t & 63;
    const int w    = __builtin_amdgcn_readfirstlane(t >> 6);

    __shared__ float qrow[256];
    __shared__ float red[512];
    __shared__ float sh_wv[32];
    __shared__ float sh_a[128];
    __shared__ float sh_d[32];

    // ---- stage query row (256 floats, 1/thread) ----
    qrow[t] = query[(size_t)b * 256 + t];
    __syncthreads();

    // ---- w = qrow @ W_q  (256x32), split K-dim over 8 chunks ----
    {
        const int n = t & 31, kc = t >> 5;
        float p = 0.f;
        #pragma unroll
        for (int i = 0; i < 32; ++i) {
            const int k = (kc << 5) + i;
            p += qrow[k] * W_q[k * FNN + n];
        }
        red[t] = p;
    }
    __syncthreads();
    if (t < 32) {
        float s = 0.f;
        #pragma unroll
        for (int kc = 0; kc < 8; ++kc) s += red[(kc << 5) + t];
        sh_wv[t] = s;
    }
    __syncthreads();

    // ---- main stream: cv accumulation fused with shifted copy ----
    float cv0[8], cv1[8];
    #pragma unroll
    for (int j = 0; j < 8; ++j) { cv0[j] = 0.f; cv1[j] = 0.f; }

    const float* asp = attn_states + (size_t)b * LL * AA + lane * 2;
    float*       osp = out_states  + (size_t)b * (LL - 1) * AA + lane * 2;
    const float* kp  = conv_k + w * 8;   // wave-uniform K slice

    #pragma unroll 4
    for (int l = 0; l < LL; ++l) {
        const float2 av = *(const float2*)(asp + (size_t)l * AA);
        const float4 ka = *(const float4*)(kp + l * FNN);
        const float4 kb = *(const float4*)(kp + l * FNN + 4);
        const float kk[8] = {ka.x, ka.y, ka.z, ka.w, kb.x, kb.y, kb.z, kb.w};
        #pragma unroll
        for (int j = 0; j < 8; ++j) {
            cv0[j] += av.x * kk[j];
            cv1[j] += av.y * kk[j];
        }
        // shifted copy: row l -> out row l-1, one wave per row
        if (((l & 3) == w) && (l > 0)) {
            *(float2*)(osp + (size_t)(l - 1) * AA) = av;
        }
    }

    // conv bias (zeros in practice, but keep exact semantics)
    #pragma unroll
    for (int j = 0; j < 8; ++j) {
        const float cb = conv_b[w * 8 + j];
        cv0[j] += cb;
        cv1[j] += cb;
    }

    // ---- s = cv . w ; a = sigmoid(s) ----
    float wv[8];
    #pragma unroll
    for (int j = 0; j < 8; ++j) wv[j] = sh_wv[w * 8 + j];
    float sp0 = 0.f, sp1 = 0.f;
    #pragma unroll
    for (int j = 0; j < 8; ++j) { sp0 += cv0[j] * wv[j]; sp1 += cv1[j] * wv[j]; }
    red[(lane * 2 + 0) * 4 + w] = sp0;
    red[(lane * 2 + 1) * 4 + w] = sp1;
    __syncthreads();
    if (t < 128) {
        const float s = red[t * 4] + red[t * 4 + 1] + red[t * 4 + 2] + red[t * 4 + 3];
        sh_a[t] = 1.f / (1.f + expf(-s));
    }
    __syncthreads();

    // ---- d = a . cv  (reduce over f: 2 per lane, then 64 lanes) ----
    const float a0 = sh_a[lane * 2], a1 = sh_a[lane * 2 + 1];
    float dp[8];
    #pragma unroll
    for (int j = 0; j < 8; ++j) dp[j] = a0 * cv0[j] + a1 * cv1[j];
    #pragma unroll
    for (int off = 32; off > 0; off >>= 1) {
        #pragma unroll
        for (int j = 0; j < 8; ++j) dp[j] += __shfl_xor(dp[j], off);
    }
    if (lane == 0) {
        #pragma unroll
        for (int j = 0; j < 8; ++j) sh_d[w * 8 + j] = dp[j];
    }
    __syncthreads();

    // ---- out0 = [qrow, d] @ W_out + b_out ----
    {
        const int m = t & 127, half = t >> 7;
        float acc = 0.f;
        const int kbase = half << 7;
        for (int k = kbase; k < kbase + 128; ++k)
            acc += qrow[k] * W_out[k * AA + m];
        if (half) {
            #pragma unroll
            for (int j = 0; j < 32; ++j)
                acc += sh_d[j] * W_out[(256 + j) * AA + m];
        } else {
            acc += b_out[m];
        }
        red[t] = acc;   // red last read two barriers ago — safe
    }
    __syncthreads();
    if (t < 128)
        out_attns[(size_t)b * AA + t] = red[t] + red[t + 128];
}

extern "C" void kernel_launch(void* const* d_in, const int* in_sizes, int n_in,
                              void* d_out, int out_size, void* d_ws, size_t ws_size,
                              hipStream_t stream) {
    const float* query       = (const float*)d_in[0];
    const float* attn_states = (const float*)d_in[1];
    const float* W_q         = (const float*)d_in[2];
    const float* conv_k      = (const float*)d_in[3];
    const float* conv_b      = (const float*)d_in[4];
    const float* W_out       = (const float*)d_in[5];
    const float* b_out       = (const float*)d_in[6];

    float* out_attns  = (float*)d_out;                         // B*A
    float* out_states = (float*)d_out + (size_t)BB * AA;       // B*(L-1)*A

    tpa_fused<<<BB, 256, 0, stream>>>(query, attn_states, W_q, conv_k, conv_b,
                                      W_out, b_out, out_attns, out_states);
}

// Round 2
// 666.267 us; speedup vs baseline: 1.0405x; 1.0405x over previous
//
#include <hip/hip_runtime.h>
#include <math.h>

// Problem constants (fixed by the reference)
#define BB  4096
#define LL  168
#define AA  128
#define FNN 32

typedef float f16v __attribute__((ext_vector_type(16)));

// One block per batch sample. 256 threads = 4 waves.
// Wave wid: p = wid>>1 selects row parity (rows l = 2i+p), h = wid&1 selects
// n-half [16h, 16h+16). Lane ln owns f = {2ln, 2ln+1}.
// conv_k access is wave-uniform -> scalar loads (s_load), lgkmcnt stream.
__global__ __launch_bounds__(256, 4)
void tpa_fused(const float* __restrict__ query,
               const float* __restrict__ attn_states,
               const float* __restrict__ W_q,
               const float* __restrict__ conv_k,
               const float* __restrict__ conv_b,
               const float* __restrict__ W_out,
               const float* __restrict__ b_out,
               float* __restrict__ out_attns,   // (B, A)
               float* __restrict__ out_states)  // (B, L-1, A)
{
    const int b    = blockIdx.x;
    const int t    = threadIdx.x;
    const int lane = t & 63;
    const int wid  = __builtin_amdgcn_readfirstlane(t >> 6);
    const int h    = wid & 1;    // n-half
    const int p    = wid >> 1;   // row parity

    __shared__ float qrow[256];
    __shared__ float red[512];
    __shared__ float sh_wv[32];
    __shared__ float sh_a[128];
    __shared__ float sh_dp[64];
    __shared__ float sh_d[32];

    // ---- stage query row ----
    qrow[t] = query[(size_t)b * 256 + t];
    __syncthreads();

    // ---- wv = qrow @ W_q (256x32), K-dim split over 8 chunks ----
    {
        const int n = t & 31, kc = t >> 5;
        float pp = 0.f;
        #pragma unroll
        for (int i = 0; i < 32; ++i) {
            const int k = (kc << 5) + i;
            pp += qrow[k] * W_q[k * FNN + n];
        }
        red[t] = pp;
    }
    __syncthreads();
    if (t < 32) {
        float s = 0.f;
        #pragma unroll
        for (int kc = 0; kc < 8; ++kc) s += red[(kc << 5) + t];
        sh_wv[t] = s;
    }
    __syncthreads();

    float wvv[16];
    #pragma unroll
    for (int n = 0; n < 16; ++n) wvv[n] = sh_wv[h * 16 + n];

    // ---- main stream: partial cv over this wave's row parity ----
    float cv0[16], cv1[16];
    #pragma unroll
    for (int n = 0; n < 16; ++n) { cv0[n] = 0.f; cv1[n] = 0.f; }

    const float* asp = attn_states + (size_t)b * (LL * AA) + p * AA + lane * 2;
    float*       osp = out_states  + (size_t)b * ((LL - 1) * AA) + lane * 2;
    const float* kwp = conv_k + h * 16;            // wave-uniform
    const bool dostore = (h == 0);                 // waves 0 (even rows) & 2 (odd rows)

    // depth-2 ping-pong software pipeline over 84 row-pair iterations
    float2 a_cur = *(const float2*)asp;                       // row p
    f16v   k_cur = *(const f16v*)(kwp + p * FNN);             // K[p, 16h:16h+16]
    float2 a_nxt;
    f16v   k_nxt;

    for (int i = 0; i < 84; i += 2) {
        // prefetch iteration i+1 (row 2(i+1)+p)
        a_nxt = *(const float2*)(asp + (size_t)(i + 1) * 256);
        k_nxt = *(const f16v*)(kwp + (size_t)(2 * (i + 1) + p) * FNN);
        if (dostore) {
            const int ro = 2 * i + p - 1;          // shifted dest row
            if (ro >= 0) *(float2*)(osp + (size_t)ro * AA) = a_cur;
        }
        #pragma unroll
        for (int n = 0; n < 16; ++n) {
            cv0[n] += a_cur.x * k_cur[n];
            cv1[n] += a_cur.y * k_cur[n];
        }
        // prefetch iteration i+2
        if (i + 2 < 84) {
            a_cur = *(const float2*)(asp + (size_t)(i + 2) * 256);
            k_cur = *(const f16v*)(kwp + (size_t)(2 * (i + 2) + p) * FNN);
        }
        if (dostore) {
            const int ro = 2 * i + 1 + p;          // = 2(i+1)+p-1, always >= 1
            *(float2*)(osp + (size_t)ro * AA) = a_nxt;
        }
        #pragma unroll
        for (int n = 0; n < 16; ++n) {
            cv0[n] += a_nxt.x * k_nxt[n];
            cv1[n] += a_nxt.y * k_nxt[n];
        }
    }

    // conv bias: add once per (f,n) -> only parity-0 waves
    if (p == 0) {
        #pragma unroll
        for (int n = 0; n < 16; ++n) {
            const float cb = conv_b[h * 16 + n];
            cv0[n] += cb;
            cv1[n] += cb;
        }
    }

    // ---- s = cv . wv ; a = sigmoid(s) ----
    float sp0 = 0.f, sp1 = 0.f;
    #pragma unroll
    for (int n = 0; n < 16; ++n) { sp0 += cv0[n] * wvv[n]; sp1 += cv1[n] * wvv[n]; }
    red[(lane * 2 + 0) * 4 + wid] = sp0;
    red[(lane * 2 + 1) * 4 + wid] = sp1;
    __syncthreads();
    if (t < 128) {
        const float s = red[t * 4] + red[t * 4 + 1] + red[t * 4 + 2] + red[t * 4 + 3];
        sh_a[t] = 1.f / (1.f + expf(-s));
    }
    __syncthreads();

    // ---- d[n] = sum_f a[f] * cv[f][n] ----
    const float a0 = sh_a[lane * 2], a1 = sh_a[lane * 2 + 1];
    float dp[16];
    #pragma unroll
    for (int n = 0; n < 16; ++n) dp[n] = a0 * cv0[n] + a1 * cv1[n];
    #pragma unroll
    for (int off = 32; off > 0; off >>= 1) {
        #pragma unroll
        for (int n = 0; n < 16; ++n) dp[n] += __shfl_xor(dp[n], off);
    }
    if (lane == 0) {
        #pragma unroll
        for (int n = 0; n < 16; ++n) sh_dp[wid * 16 + n] = dp[n];
    }
    __syncthreads();
    if (t < 32) sh_d[t] = sh_dp[t] + sh_dp[t + 32];   // combine row parities
    __syncthreads();

    // ---- out0 = [qrow, d] @ W_out + b_out ----
    {
        const int m = t & 127, khalf = t >> 7;
        float acc = 0.f;
        const int kbase = khalf << 7;
        #pragma unroll 4
        for (int k = kbase; k < kbase + 128; ++k)
            acc += qrow[k] * W_out[k * AA + m];
        if (khalf) {
            #pragma unroll
            for (int j = 0; j < 32; ++j)
                acc += sh_d[j] * W_out[(256 + j) * AA + m];
        } else {
            acc += b_out[m];
        }
        red[t] = acc;   // all prior red reads completed two barriers ago
    }
    __syncthreads();
    if (t < 128)
        out_attns[(size_t)b * AA + t] = red[t] + red[t + 128];
}

extern "C" void kernel_launch(void* const* d_in, const int* in_sizes, int n_in,
                              void* d_out, int out_size, void* d_ws, size_t ws_size,
                              hipStream_t stream) {
    const float* query       = (const float*)d_in[0];
    const float* attn_states = (const float*)d_in[1];
    const float* W_q         = (const float*)d_in[2];
    const float* conv_k      = (const float*)d_in[3];
    const float* conv_b      = (const float*)d_in[4];
    const float* W_out       = (const float*)d_in[5];
    const float* b_out       = (const float*)d_in[6];

    float* out_attns  = (float*)d_out;                         // B*A
    float* out_states = (float*)d_out + (size_t)BB * AA;       // B*(L-1)*A

    tpa_fused<<<BB, 256, 0, stream>>>(query, attn_states, W_q, conv_k, conv_b,
                                      W_out, b_out, out_attns, out_states);
}